// Round 1
// baseline (2450.292 us; speedup 1.0000x reference)
//
#include <hip/hip_runtime.h>
#include <hip/hip_bf16.h>
#include <stdint.h>

#define N_LEVELS   16
#define N_FEATS    2
#define LOG2_T     19
#define TABLE_SIZE (1u << LOG2_T)
#define PRIME_Y    2654435761u
#define PRIME_Z    805459861u

// One thread per point: hash-grid encode (fp32) + fused 32->64->64->1 MLP (fp32).
// Weights are wave-uniform loads -> expect s_load + SGPR-operand FMA.
__global__ __launch_bounds__(256)
void hashgrid_mlp_kernel(const float* __restrict__ x,           // [N,3]
                         const float* __restrict__ tables,      // [16, T, 2]
                         const float* __restrict__ resolutions, // [16]
                         const float* __restrict__ W1,          // [32,64]
                         const float* __restrict__ b1,          // [64]
                         const float* __restrict__ W2,          // [64,64]
                         const float* __restrict__ b2,          // [64]
                         const float* __restrict__ W3,          // [64,1]
                         const float* __restrict__ b3,          // [1]
                         float* __restrict__ out,               // [N]
                         int n)
{
    const int i = blockIdx.x * blockDim.x + threadIdx.x;
    if (i >= n) return;

    // map [-1,1] -> [0,1], same fp32 ops as reference (x/2 + 0.5)
    const float x0 = x[3 * i + 0] * 0.5f + 0.5f;
    const float x1 = x[3 * i + 1] * 0.5f + 0.5f;
    const float x2 = x[3 * i + 2] * 0.5f + 0.5f;

    float a[2 * N_LEVELS];

    #pragma unroll
    for (int l = 0; l < N_LEVELS; ++l) {
        const float res = resolutions[l];
        const float px = x0 * res, py = x1 * res, pz = x2 * res;
        const float fx = floorf(px), fy = floorf(py), fz = floorf(pz);
        const float wx = px - fx, wy = py - fy, wz = pz - fz;
        const uint32_t cx = (uint32_t)fx;
        const uint32_t cy = (uint32_t)fy;
        const uint32_t cz = (uint32_t)fz;

        // hash contributions per dim (prime_x == 1)
        const uint32_t hx0 = cx,              hx1 = cx + 1u;
        const uint32_t hy0 = cy * PRIME_Y,    hy1 = hy0 + PRIME_Y;
        const uint32_t hz0 = cz * PRIME_Z,    hz1 = hz0 + PRIME_Z;

        const float wx0 = 1.0f - wx, wy0 = 1.0f - wy, wz0 = 1.0f - wz;

        const float* __restrict__ tab = tables + (size_t)l * (size_t)TABLE_SIZE * 2u;

        float f0 = 0.0f, f1 = 0.0f;
        #pragma unroll
        for (int c = 0; c < 8; ++c) {
            const uint32_t h = ((c & 1) ? hx1 : hx0) ^
                               ((c & 2) ? hy1 : hy0) ^
                               ((c & 4) ? hz1 : hz0);
            const uint32_t idx = h & (TABLE_SIZE - 1u);
            const float2 fv = *(const float2*)(tab + 2u * idx);
            const float wgt = ((c & 1) ? wx : wx0) *
                              ((c & 2) ? wy : wy0) *
                              ((c & 4) ? wz : wz0);
            f0 = fmaf(wgt, fv.x, f0);
            f1 = fmaf(wgt, fv.y, f1);
        }
        a[2 * l + 0] = f0;
        a[2 * l + 1] = f1;
    }

    // ---- layer 1: [32] @ [32,64] + b1, relu ----
    float h1[64];
    #pragma unroll
    for (int j = 0; j < 64; ++j) h1[j] = b1[j];
    for (int k = 0; k < 32; ++k) {
        const float ak = a[k];
        const float* __restrict__ w1row = W1 + k * 64;
        #pragma unroll
        for (int j = 0; j < 64; ++j) h1[j] = fmaf(ak, w1row[j], h1[j]);
    }
    #pragma unroll
    for (int j = 0; j < 64; ++j) h1[j] = fmaxf(h1[j], 0.0f);

    // ---- layer 2 + 3 fused, in two 32-wide halves to cap live VGPRs ----
    float accum = b3[0];
    #pragma unroll
    for (int half = 0; half < 2; ++half) {
        float h2[32];
        #pragma unroll
        for (int j = 0; j < 32; ++j) h2[j] = b2[half * 32 + j];
        for (int k = 0; k < 64; ++k) {
            const float hk = h1[k];
            const float* __restrict__ w2row = W2 + k * 64 + half * 32;
            #pragma unroll
            for (int j = 0; j < 32; ++j) h2[j] = fmaf(hk, w2row[j], h2[j]);
        }
        #pragma unroll
        for (int j = 0; j < 32; ++j)
            accum = fmaf(fmaxf(h2[j], 0.0f), W3[half * 32 + j], accum);
    }

    out[i] = accum;
}

extern "C" void kernel_launch(void* const* d_in, const int* in_sizes, int n_in,
                              void* d_out, int out_size, void* d_ws, size_t ws_size,
                              hipStream_t stream) {
    const float* x           = (const float*)d_in[0];
    const float* tables      = (const float*)d_in[1];
    const float* resolutions = (const float*)d_in[2];
    const float* W1          = (const float*)d_in[3];
    const float* b1          = (const float*)d_in[4];
    const float* W2          = (const float*)d_in[5];
    const float* b2          = (const float*)d_in[6];
    const float* W3          = (const float*)d_in[7];
    const float* b3          = (const float*)d_in[8];
    float* out               = (float*)d_out;

    const int n = out_size;  // 2,000,000 points
    const int block = 256;
    const int grid = (n + block - 1) / block;
    hashgrid_mlp_kernel<<<grid, block, 0, stream>>>(
        x, tables, resolutions, W1, b1, W2, b2, W3, b3, out, n);
}

// Round 2
// 1713.877 us; speedup vs baseline: 1.4297x; 1.4297x over previous
//
#include <hip/hip_runtime.h>
#include <hip/hip_bf16.h>
#include <stdint.h>

#define N_LEVELS   16
#define LOG2_T     19
#define TABLE_SIZE (1u << LOG2_T)
#define PRIME_Y    2654435761u
#define PRIME_Z    805459861u

// One thread per point. Weights staged in LDS (25 KB/block); MLP fully
// unrolled so all weight reads are ds_read_b128 at immediate offsets
// (wave-uniform broadcast -> no bank conflicts, no per-load address VALU).
__global__ __launch_bounds__(256, 4)
void hashgrid_mlp_kernel(const float* __restrict__ x,           // [N,3]
                         const float* __restrict__ tables,      // [16, T, 2]
                         const float* __restrict__ resolutions, // [16]
                         const float* __restrict__ W1,          // [32,64]
                         const float* __restrict__ b1,          // [64]
                         const float* __restrict__ W2,          // [64,64]
                         const float* __restrict__ b2,          // [64]
                         const float* __restrict__ W3,          // [64,1]
                         const float* __restrict__ b3,          // [1]
                         float* __restrict__ out,               // [N]
                         int n)
{
    __shared__ float sW1[32 * 64];
    __shared__ float sW2[64 * 64];
    __shared__ float sW3[64];
    __shared__ float sB1[64];
    __shared__ float sB2[64];
    __shared__ float sB3;

    // ---- cooperative one-time weight staging ----
    {
        const int t = threadIdx.x;
        #pragma unroll
        for (int j = 0; j < 32 * 64; j += 256) sW1[j + t] = W1[j + t];
        #pragma unroll
        for (int j = 0; j < 64 * 64; j += 256) sW2[j + t] = W2[j + t];
        if (t < 64) {
            sW3[t] = W3[t];
            sB1[t] = b1[t];
            sB2[t] = b2[t];
        }
        if (t == 64) sB3 = b3[0];
    }
    __syncthreads();

    const int i = blockIdx.x * blockDim.x + threadIdx.x;
    if (i >= n) return;

    const float x0 = x[3 * i + 0] * 0.5f + 0.5f;
    const float x1 = x[3 * i + 1] * 0.5f + 0.5f;
    const float x2 = x[3 * i + 2] * 0.5f + 0.5f;

    // ---- hash-grid encode: 16 levels x 8 corner gathers ----
    float a[2 * N_LEVELS];

    #pragma unroll
    for (int l = 0; l < N_LEVELS; ++l) {
        const float res = resolutions[l];
        const float px = x0 * res, py = x1 * res, pz = x2 * res;
        const float fx = floorf(px), fy = floorf(py), fz = floorf(pz);
        const float wx = px - fx, wy = py - fy, wz = pz - fz;
        const uint32_t cx = (uint32_t)fx;
        const uint32_t cy = (uint32_t)fy;
        const uint32_t cz = (uint32_t)fz;

        const uint32_t hx0 = cx,           hx1 = cx + 1u;
        const uint32_t hy0 = cy * PRIME_Y, hy1 = hy0 + PRIME_Y;
        const uint32_t hz0 = cz * PRIME_Z, hz1 = hz0 + PRIME_Z;

        const float wx0 = 1.0f - wx, wy0 = 1.0f - wy, wz0 = 1.0f - wz;

        const float* __restrict__ tab = tables + (size_t)l * (size_t)TABLE_SIZE * 2u;

        float f0 = 0.0f, f1 = 0.0f;
        #pragma unroll
        for (int c = 0; c < 8; ++c) {
            const uint32_t h = ((c & 1) ? hx1 : hx0) ^
                               ((c & 2) ? hy1 : hy0) ^
                               ((c & 4) ? hz1 : hz0);
            const uint32_t idx = h & (TABLE_SIZE - 1u);
            const float2 fv = *(const float2*)(tab + 2u * idx);
            const float wgt = ((c & 1) ? wx : wx0) *
                              ((c & 2) ? wy : wy0) *
                              ((c & 4) ? wz : wz0);
            f0 = fmaf(wgt, fv.x, f0);
            f1 = fmaf(wgt, fv.y, f1);
        }
        a[2 * l + 0] = f0;
        a[2 * l + 1] = f1;
    }

    // ---- layer 1: [32] @ [32,64] + b1, relu (fully unrolled, LDS b128) ----
    float h1[64];
    #pragma unroll
    for (int j = 0; j < 64; ++j) h1[j] = sB1[j];
    #pragma unroll
    for (int k = 0; k < 32; ++k) {
        const float ak = a[k];
        #pragma unroll
        for (int j4 = 0; j4 < 16; ++j4) {
            const float4 w = *(const float4*)&sW1[k * 64 + j4 * 4];
            h1[j4 * 4 + 0] = fmaf(ak, w.x, h1[j4 * 4 + 0]);
            h1[j4 * 4 + 1] = fmaf(ak, w.y, h1[j4 * 4 + 1]);
            h1[j4 * 4 + 2] = fmaf(ak, w.z, h1[j4 * 4 + 2]);
            h1[j4 * 4 + 3] = fmaf(ak, w.w, h1[j4 * 4 + 3]);
        }
    }
    #pragma unroll
    for (int j = 0; j < 64; ++j) h1[j] = fmaxf(h1[j], 0.0f);

    // ---- layer 2 + 3 fused, two 32-wide halves to cap live VGPRs ----
    float accum = sB3;
    #pragma unroll
    for (int half = 0; half < 2; ++half) {
        float h2[32];
        #pragma unroll
        for (int j = 0; j < 32; ++j) h2[j] = sB2[half * 32 + j];
        #pragma unroll
        for (int k = 0; k < 64; ++k) {
            const float hk = h1[k];
            #pragma unroll
            for (int j4 = 0; j4 < 8; ++j4) {
                const float4 w = *(const float4*)&sW2[k * 64 + half * 32 + j4 * 4];
                h2[j4 * 4 + 0] = fmaf(hk, w.x, h2[j4 * 4 + 0]);
                h2[j4 * 4 + 1] = fmaf(hk, w.y, h2[j4 * 4 + 1]);
                h2[j4 * 4 + 2] = fmaf(hk, w.z, h2[j4 * 4 + 2]);
                h2[j4 * 4 + 3] = fmaf(hk, w.w, h2[j4 * 4 + 3]);
            }
        }
        #pragma unroll
        for (int j4 = 0; j4 < 8; ++j4) {
            const float4 w3 = *(const float4*)&sW3[half * 32 + j4 * 4];
            accum = fmaf(fmaxf(h2[j4 * 4 + 0], 0.0f), w3.x, accum);
            accum = fmaf(fmaxf(h2[j4 * 4 + 1], 0.0f), w3.y, accum);
            accum = fmaf(fmaxf(h2[j4 * 4 + 2], 0.0f), w3.z, accum);
            accum = fmaf(fmaxf(h2[j4 * 4 + 3], 0.0f), w3.w, accum);
        }
    }

    out[i] = accum;
}

extern "C" void kernel_launch(void* const* d_in, const int* in_sizes, int n_in,
                              void* d_out, int out_size, void* d_ws, size_t ws_size,
                              hipStream_t stream) {
    const float* x           = (const float*)d_in[0];
    const float* tables      = (const float*)d_in[1];
    const float* resolutions = (const float*)d_in[2];
    const float* W1          = (const float*)d_in[3];
    const float* b1          = (const float*)d_in[4];
    const float* W2          = (const float*)d_in[5];
    const float* b2          = (const float*)d_in[6];
    const float* W3          = (const float*)d_in[7];
    const float* b3          = (const float*)d_in[8];
    float* out               = (float*)d_out;

    const int n = out_size;  // 2,000,000
    const int block = 256;
    const int grid = (n + block - 1) / block;
    hashgrid_mlp_kernel<<<grid, block, 0, stream>>>(
        x, tables, resolutions, W1, b1, W2, b2, W3, b3, out, n);
}